// Round 13
// baseline (502.110 us; speedup 1.0000x reference)
//
#include <hip/hip_runtime.h>
#include <hip/hip_bf16.h>
#include <hip/hip_fp16.h>

// LSTM: B=512, T=512, I=128, H=256, gates G=4H=1024 (PyTorch i,f,g,o order).
// Round-13: per-SIMD wave skew (s_sleep 0/320/640/960 cyc after each barrier)
// serializes waves' MFMA-cluster occupancy of the matrix pipe so each wave's
// EW hides under later waves' MFMAs (m114 pipe overlap), instead of all EWs
// bunching after cyc-1306 and serializing on the VALU pipe. Breadth-first
// MFMA (kt-outer) removes intra-wave dependency stalls. Bit-exact vs R12.

typedef __attribute__((ext_vector_type(4))) float f32x4;
typedef __attribute__((ext_vector_type(8))) _Float16 f16x8;
typedef __attribute__((ext_vector_type(4))) unsigned int u32x4;
typedef __attribute__((ext_vector_type(4))) int i32x4;

static __device__ __forceinline__ float h2f(unsigned short u) {
  return (float)__builtin_bit_cast(_Float16, u);
}
static __device__ __forceinline__ unsigned short f2h(float f) {
  return __builtin_bit_cast(unsigned short, (_Float16)f);
}
static __device__ __forceinline__ float fast_sigmoid(float x) {
  return __builtin_amdgcn_rcpf(1.0f + __builtin_amdgcn_exp2f(-1.44269504f * x));
}
static __device__ __forceinline__ float fast_tanh(float x) {
  return 1.0f - 2.0f * __builtin_amdgcn_rcpf(1.0f + __builtin_amdgcn_exp2f(2.88539008f * x));
}

// ---------------------------------------------------------------- prep kernels
// scl layout (floats): [0]=sw, [1]=sh, [8..135] whh partials, [136..199] h0.
__global__ __launch_bounds__(256) void prep1(
    const float* __restrict__ whh, const float* __restrict__ h0,
    const float* __restrict__ wih, const float* __restrict__ bih,
    const float* __restrict__ bhh,
    float* __restrict__ scl, unsigned short* __restrict__ wih_h,
    float* __restrict__ bcv) {
  const int b = blockIdx.x, tid = threadIdx.x;
  if (b < 192) {
    __shared__ float s[256];
    const float* src = (b < 128) ? whh : h0;
    int base = (b < 128) ? b * 2048 : (b - 128) * 2048;
    float m = 0.f;
#pragma unroll
    for (int i = 0; i < 8; ++i) m = fmaxf(m, fabsf(src[base + i * 256 + tid]));
    s[tid] = m; __syncthreads();
    for (int w = 128; w > 0; w >>= 1) {
      if (tid < w) s[tid] = fmaxf(s[tid], s[tid + w]);
      __syncthreads();
    }
    if (tid == 0) scl[8 + b] = s[0];
  } else {
    // w_ih cast + gate-row interleave: dst row q <- src row (q&3)*256 + (q>>2)
    int i = ((b - 192) * 256 + tid) * 4;  // over 131072
    int q = i >> 7, k = i & 127;
    int p = (q & 3) * 256 + (q >> 2);
    f32x4 v = *(const f32x4*)(wih + p * 128 + k);
    ushort4 pk;
    pk.x = f2h(v[0]); pk.y = f2h(v[1]); pk.z = f2h(v[2]); pk.w = f2h(v[3]);
    *(ushort4*)(wih_h + i) = pk;
    if (b == 192) {
      for (int q2 = tid; q2 < 1024; q2 += 256) {
        int p2 = (q2 & 3) * 256 + (q2 >> 2);
        bcv[q2] = bih[p2] + bhh[p2];
      }
    }
  }
}

__global__ __launch_bounds__(256) void prep2(
    const float* __restrict__ whh, const float* __restrict__ h0,
    const float* __restrict__ c0, float* __restrict__ scl,
    signed char* __restrict__ wq, signed char* __restrict__ hst,
    float* __restrict__ cst) {
  __shared__ float s[256];
  const int b = blockIdx.x, tid = threadIdx.x;
  float v = (tid < 128) ? scl[8 + tid] : 0.f;
  s[tid] = v; __syncthreads();
  for (int w = 128; w > 0; w >>= 1) {
    if (tid < w) s[tid] = fmaxf(s[tid], s[tid + w]);
    __syncthreads();
  }
  float sw = s[0]; __syncthreads();
  v = (tid < 64) ? scl[136 + tid] : 0.f;
  s[tid] = v; __syncthreads();
  for (int w = 128; w > 0; w >>= 1) {
    if (tid < w) s[tid] = fmaxf(s[tid], s[tid + w]);
    __syncthreads();
  }
  float sh = s[0];
  if (b == 0 && tid == 0) { scl[0] = sw; scl[1] = sh; }

  // quantize w_hh (plain layout: row n = gate*256 + col)
  const float invw = 127.0f / sw;
  int base = b * 1024;
#pragma unroll
  for (int i = 0; i < 4; ++i) {
    int idx = base + i * 256 + tid;
    int q = (int)rintf(whh[idx] * invw);
    wq[idx] = (signed char)max(-127, min(127, q));
  }
  // state init
  const float invh = 127.0f / sh;
  int sb = b * 512;
#pragma unroll
  for (int i = 0; i < 2; ++i) {
    int idx = sb + i * 256 + tid;
    int q = (int)rintf(h0[idx] * invh);
    hst[idx] = (signed char)max(-127, min(127, q));
    cst[idx] = c0[idx];
  }
}

// ---------------------------------------------------------------- prologue gemm
__global__ __launch_bounds__(256) void xgemm(
    const float* __restrict__ x, const unsigned short* __restrict__ wih,
    const float* __restrict__ bconv,
    unsigned short* __restrict__ xg, int t0, int tclog) {
  __shared__ unsigned short Ash[128 * 128];
  __shared__ unsigned short Bsh[128 * 128];

  const int tid  = threadIdx.x;
  const int lane = tid & 63;
  const int wv   = tid >> 6;
  const int c16  = lane & 15;
  const int gq   = lane >> 4;
  const long m0  = (long)blockIdx.x * 128;
  const int tcm  = (1 << tclog) - 1;

#pragma unroll
  for (int i = 0; i < 16; ++i) {
    int fidx = (i * 256 + tid) * 4;
    int row = fidx >> 7, k = fidx & 127;
    long cr = m0 + row;
    long b  = cr >> tclog;
    long tl = cr & tcm;
    f32x4 v = *(const f32x4*)(x + ((size_t)b * 512 + t0 + tl) * 128 + k);
    ushort4 pk;
    pk.x = f2h(v[0]); pk.y = f2h(v[1]); pk.z = f2h(v[2]); pk.w = f2h(v[3]);
    int byte = (row * 256 + k * 2) ^ ((row & 7) << 4);
    *(ushort4*)((char*)Ash + byte) = pk;
  }

  const int mh = (wv >> 1) * 64;
  const int nh = (wv & 1) * 64;

  for (int nc = 0; nc < 8; ++nc) {
    __syncthreads();
    {
      const char* wb = (const char*)(wih + nc * 128 * 128);
#pragma unroll
      for (int i = 0; i < 8; ++i) {
        int idx16 = i * 256 + tid;
        int row = idx16 >> 4, ch = idx16 & 15;
        int srcoff = row * 256 + ((ch * 16) ^ ((row & 7) << 4));
        u32x4 v = *(const u32x4*)(wb + srcoff);
        *(u32x4*)((char*)Bsh + idx16 * 16) = v;
      }
    }
    __syncthreads();

    float bias_v[4];
#pragma unroll
    for (int nt = 0; nt < 4; ++nt)
      bias_v[nt] = bconv[nc * 128 + nh + nt * 16 + c16];

    f16x8 af[4][4], bfr[4][4];
#pragma unroll
    for (int sm = 0; sm < 4; ++sm)
#pragma unroll
      for (int kt = 0; kt < 4; ++kt) {
        int m = mh + sm * 16 + c16;
        int byte = (m * 256 + (kt * 32 + gq * 8) * 2) ^ ((m & 7) << 4);
        af[sm][kt] = __builtin_bit_cast(f16x8, *(const u32x4*)((const char*)Ash + byte));
      }
#pragma unroll
    for (int nt = 0; nt < 4; ++nt)
#pragma unroll
      for (int kt = 0; kt < 4; ++kt) {
        int n = nh + nt * 16 + c16;
        int byte = (n * 256 + (kt * 32 + gq * 8) * 2) ^ ((n & 7) << 4);
        bfr[nt][kt] = __builtin_bit_cast(f16x8, *(const u32x4*)((const char*)Bsh + byte));
      }

    f32x4 acc[4][4];
#pragma unroll
    for (int sm = 0; sm < 4; ++sm)
#pragma unroll
      for (int nt = 0; nt < 4; ++nt) { f32x4 z = {0.f, 0.f, 0.f, 0.f}; acc[sm][nt] = z; }
#pragma unroll
    for (int sm = 0; sm < 4; ++sm)
#pragma unroll
      for (int nt = 0; nt < 4; ++nt)
#pragma unroll
        for (int kt = 0; kt < 4; ++kt)
          acc[sm][nt] = __builtin_amdgcn_mfma_f32_16x16x32_f16(af[sm][kt], bfr[nt][kt], acc[sm][nt], 0, 0, 0);

#pragma unroll
    for (int sm = 0; sm < 4; ++sm)
#pragma unroll
      for (int nt = 0; nt < 4; ++nt) {
        long row = m0 + mh + sm * 16 + gq * 4;
        int gcol = nc * 128 + nh + nt * 16 + c16;
#pragma unroll
        for (int r = 0; r < 4; ++r)
          xg[(size_t)(row + r) * 1024 + gcol] = f2h(acc[sm][nt][r] + bias_v[nt]);
      }
  }
}

// ---------------------------------------------------------------- fused kernel
// 1024 threads. blocks 0-127: lstm chunk c (4 rows, 16 waves, 1 output/lane).
// blocks 128-255: xgemm chunk c+1.
__global__ __launch_bounds__(1024)
void fused_chunk(
    const unsigned short* __restrict__ xgc, const signed char* __restrict__ wq,
    const float* __restrict__ scales, signed char* __restrict__ hst,
    float* __restrict__ cst, float* __restrict__ out, int Tc, int first, int last,
    const float* __restrict__ x, const unsigned short* __restrict__ wih,
    const float* __restrict__ bconv, unsigned short* __restrict__ xgn,
    int t0n, int tclog, int do_x) {
  __shared__ char smem[65536];

  const int tid  = threadIdx.x;
  const int lane = tid & 63;
  const int wv   = tid >> 6;      // 0..15
  const int c16  = lane & 15;
  const int gq   = lane >> 4;     // 0..3

  if (blockIdx.x < 128) {
    // ------------------------------ LSTM: rows 0..3 at M-rows {0,4,8,12}
    signed char (*hb)[1152] = (signed char (*)[1152])smem;  // [buf][4 x 288B]
    const int b0 = blockIdx.x * 4;
    const int col = wv * 16 + c16;          // this lane's single output col
    float cv = cst[(b0 + gq) * 256 + col];  // output row = gq

    const float sw   = scales[0] * (1.0f / 127.0f);
    const float facR = sw * (1.0f / 127.0f);
    const float fac0 = first ? sw * (scales[1] * (1.0f / 127.0f)) : facR;

    // weights: gate g, n = g*256 + col, k = kt*64 + gq*16 -> 64 VGPR total
    i32x4 wf[4][4];
#pragma unroll
    for (int g = 0; g < 4; ++g)
#pragma unroll
      for (int kt = 0; kt < 4; ++kt)
        wf[g][kt] = *(const i32x4*)(wq + (g * 256 + col) * 256 + kt * 64 + gq * 16);
#pragma unroll
    for (int g = 0; g < 4; ++g)
#pragma unroll
      for (int kt = 0; kt < 4; ++kt)
        asm volatile("" : "+v"(wf[g][kt]));

    // init hb[0]: rows 0..3 (stride 288B), cols 0..255
    {
      int row = tid >> 8, cc = tid & 255;
      hb[0][row * 288 + cc] = hst[(b0 + row) * 256 + cc];
    }

    // per-lane xg: [row=gq][t][col*4 + gate], 8 B/lane/step
    const char* pxp = (const char*)xgc +
        (((size_t)(b0 + gq) * Tc) * 1024 + (size_t)col * 4) * 2;

    const bool mrow = (c16 & 3) == 0;  // A-lanes: M-rows 0,4,8,12
    const signed char* hpA = &hb[0][(c16 >> 2) * 288 + gq * 16];  // read buf 0
    const signed char* hpB = &hb[1][(c16 >> 2) * 288 + gq * 16];  // read buf 1
    signed char* hwA = &hb[1][gq * 288 + col];  // write buf 1 (even steps)
    signed char* hwB = &hb[0][gq * 288 + col];  // write buf 0 (odd steps)

    // SIMD-local wave index (robust to either wave->SIMD mapping):
    const int si = (wv >> 2) ^ (wv & 3);

    i32x4 af[4];
#pragma unroll
    for (int kt = 0; kt < 4; ++kt) { i32x4 z = {0, 0, 0, 0}; af[kt] = z; }
    const i32x4 zacc = {0, 0, 0, 0};
    int qlast = 0;

    uint2 pxA = *(const uint2*)pxp; pxp += 2048;   // t=0
    uint2 pxB;

    __syncthreads();

// stagger this wave's matrix-pipe occupancy: ~320 cyc per SIMD-local index
#define LSTM_SKEW()                                                            \
    {                                                                          \
      if (si & 1) __builtin_amdgcn_s_sleep(5);                                 \
      if (si & 2) __builtin_amdgcn_s_sleep(10);                                \
    }

// breadth-first (kt-outer): 4 independent MFMAs per round, no intra-wave
// dependency stalls; per-acc chain order unchanged (bit-exact).
#define LSTM_MFMA_CLUSTER(ACC, AF)                                            \
    {                                                                          \
      __builtin_amdgcn_s_setprio(1);                                           \
      _Pragma("unroll")                                                        \
      for (int g = 0; g < 4; ++g)                                              \
        ACC[g] = __builtin_amdgcn_mfma_i32_16x16x64_i8(AF[0], wf[g][0], zacc, 0, 0, 0); \
      _Pragma("unroll")                                                        \
      for (int kt = 1; kt < 4; ++kt)                                           \
        _Pragma("unroll")                                                      \
        for (int g = 0; g < 4; ++g)                                            \
          ACC[g] = __builtin_amdgcn_mfma_i32_16x16x64_i8(AF[kt], wf[g][kt], ACC[g], 0, 0, 0); \
      __builtin_amdgcn_s_setprio(0);                                           \
    }

#define LSTM_EW(ACC, PX, FAC, HW)                                              \
    {                                                                          \
      float xi  = h2f((unsigned short)(PX.x & 0xffff));                        \
      float xf  = h2f((unsigned short)(PX.x >> 16));                           \
      float xgv = h2f((unsigned short)(PX.y & 0xffff));                        \
      float xo  = h2f((unsigned short)(PX.y >> 16));                           \
      float gi = __builtin_fmaf((float)ACC[0][0], FAC, xi);                    \
      float gf = __builtin_fmaf((float)ACC[1][0], FAC, xf);                    \
      float gg = __builtin_fmaf((float)ACC[2][0], FAC, xgv);                   \
      float go = __builtin_fmaf((float)ACC[3][0], FAC, xo);                    \
      cv = fast_sigmoid(gf) * cv + fast_sigmoid(gi) * fast_tanh(gg);           \
      float hn = fast_sigmoid(go) * fast_tanh(cv);                             \
      qlast = (int)rintf(hn * 127.0f);                                         \
      *HW = (signed char)qlast;                                                \
    }

    for (int tt = 0; tt < Tc; tt += 2) {
      // ---------------- even step (read buf0, write buf1)
      pxB = *(const uint2*)pxp; pxp += 2048;   // xg for odd step (in flight)
      LSTM_SKEW()
      if (mrow) {
        af[0] = *(const i32x4*)(hpA);
        af[1] = *(const i32x4*)(hpA + 64);
        af[2] = *(const i32x4*)(hpA + 128);
        af[3] = *(const i32x4*)(hpA + 192);
      }
      i32x4 accA[4];
      LSTM_MFMA_CLUSTER(accA, af)
      {
        const float facE = (tt == 0) ? fac0 : facR;
        LSTM_EW(accA, pxA, facE, hwA)
      }
      __syncthreads();

      // ---------------- odd step (read buf1, write buf0)
      pxA = *(const uint2*)pxp; pxp += 2048;   // xg for next even step
      LSTM_SKEW()
      if (mrow) {
        af[0] = *(const i32x4*)(hpB);
        af[1] = *(const i32x4*)(hpB + 64);
        af[2] = *(const i32x4*)(hpB + 128);
        af[3] = *(const i32x4*)(hpB + 192);
      }
      i32x4 accB[4];
      LSTM_MFMA_CLUSTER(accB, af)
      LSTM_EW(accB, pxB, facR, hwB)
      __syncthreads();
    }
#undef LSTM_SKEW
#undef LSTM_MFMA_CLUSTER
#undef LSTM_EW

    cst[(b0 + gq) * 256 + col] = cv;
    hst[(b0 + gq) * 256 + col] = (signed char)qlast;
    if (last) out[(b0 + gq) * 256 + col] = cv;
  } else if (do_x) {
    // ------------------------------ XGEMM chunk c+1 (1024 thr, 16 waves)
    unsigned short* Ash = (unsigned short*)smem;            // 128x128 f16
    unsigned short* Bsh = (unsigned short*)(smem + 32768);  // 128x128 f16
    const int tcm    = (1 << tclog) - 1;
    const int ntiles = Tc << 2;            // (512*Tc)/128
    const int wm = wv >> 2, wn = wv & 3;   // 4x4 wave grid
    const int mh = wm * 32, nh = wn * 32;

    for (int rt = (int)blockIdx.x - 128; rt < ntiles; rt += 128) {
      const long m0 = (long)rt * 128;
      __syncthreads();  // previous tile's readers done before re-staging

#pragma unroll
      for (int i = 0; i < 4; ++i) {
        int fidx = (i * 1024 + tid) * 4;
        int row = fidx >> 7, k = fidx & 127;
        long cr = m0 + row;
        long b  = cr >> tclog;
        long tl = cr & tcm;
        f32x4 v = *(const f32x4*)(x + ((size_t)b * 512 + t0n + tl) * 128 + k);
        ushort4 pk;
        pk.x = f2h(v[0]); pk.y = f2h(v[1]); pk.z = f2h(v[2]); pk.w = f2h(v[3]);
        int byte = (row * 256 + k * 2) ^ ((row & 7) << 4);
        *(ushort4*)((char*)Ash + byte) = pk;
      }

      for (int nc = 0; nc < 8; ++nc) {
        __syncthreads();
        {
          const char* wb = (const char*)(wih + nc * 128 * 128);
#pragma unroll
          for (int i = 0; i < 2; ++i) {
            int idx16 = i * 1024 + tid;
            int row = idx16 >> 4, ch = idx16 & 15;
            int srcoff = row * 256 + ((ch * 16) ^ ((row & 7) << 4));
            u32x4 v = *(const u32x4*)(wb + srcoff);
            *(u32x4*)((char*)Bsh + idx16 * 16) = v;
          }
        }
        __syncthreads();

        float bias_v[2];
#pragma unroll
        for (int nt = 0; nt < 2; ++nt)
          bias_v[nt] = bconv[nc * 128 + nh + nt * 16 + c16];

        f16x8 af[2][4], bfr[2][4];
#pragma unroll
        for (int sm = 0; sm < 2; ++sm)
#pragma unroll
          for (int kt = 0; kt < 4; ++kt) {
            int m = mh + sm * 16 + c16;
            int byte = (m * 256 + (kt * 32 + gq * 8) * 2) ^ ((m & 7) << 4);
            af[sm][kt] = __builtin_bit_cast(f16x8, *(const u32x4*)((const char*)Ash + byte));
          }
#pragma unroll
        for (int nt = 0; nt < 2; ++nt)
#pragma unroll
          for (int kt = 0; kt < 4; ++kt) {
            int n = nh + nt * 16 + c16;
            int byte = (n * 256 + (kt * 32 + gq * 8) * 2) ^ ((n & 7) << 4);
            bfr[nt][kt] = __builtin_bit_cast(f16x8, *(const u32x4*)((const char*)Bsh + byte));
          }

        f32x4 acc[2][2];
#pragma unroll
        for (int sm = 0; sm < 2; ++sm)
#pragma unroll
          for (int nt = 0; nt < 2; ++nt) { f32x4 z = {0.f, 0.f, 0.f, 0.f}; acc[sm][nt] = z; }
#pragma unroll
        for (int sm = 0; sm < 2; ++sm)
#pragma unroll
          for (int nt = 0; nt < 2; ++nt)
#pragma unroll
            for (int kt = 0; kt < 4; ++kt)
              acc[sm][nt] = __builtin_amdgcn_mfma_f32_16x16x32_f16(af[sm][kt], bfr[nt][kt], acc[sm][nt], 0, 0, 0);

#pragma unroll
        for (int sm = 0; sm < 2; ++sm)
#pragma unroll
          for (int nt = 0; nt < 2; ++nt) {
            long row = m0 + mh + sm * 16 + gq * 4;
            int gcol = nc * 128 + nh + nt * 16 + c16;
#pragma unroll
            for (int r = 0; r < 4; ++r)
              xgn[(size_t)(row + r) * 1024 + gcol] = f2h(acc[sm][nt][r] + bias_v[nt]);
          }
      }
    }
  }
}

// ---------------------------------------------------------------- launch
extern "C" void kernel_launch(void* const* d_in, const int* in_sizes, int n_in,
                              void* d_out, int out_size, void* d_ws, size_t ws_size,
                              hipStream_t stream) {
  const float* x   = (const float*)d_in[0];
  const float* h0  = (const float*)d_in[1];
  const float* c0  = (const float*)d_in[2];
  const float* wih = (const float*)d_in[3];
  const float* whh = (const float*)d_in[4];
  const float* bih = (const float*)d_in[5];
  const float* bhh = (const float*)d_in[6];
  float* out = (float*)d_out;

  const size_t fixed = 262144u /*wih f16*/ + 262144u /*wq*/ + 131072u /*hst*/
                     + 524288u /*cst*/ + 4096u /*bconv*/ + 1024u /*scales*/;
  int tc = 128;  // ws_size caps 2 xg buffers at 2x134MB -> tc=128, NC=4
  while (tc > 4 && 2u * (size_t)512 * tc * 2048 + fixed > ws_size) tc >>= 1;
  int tclog = 31 - __builtin_clz((unsigned)tc);
  size_t bufsz = (size_t)512 * tc * 2048;

  char* ws = (char*)d_ws;
  unsigned short* xgb0  = (unsigned short*)ws;
  unsigned short* xgb1  = (unsigned short*)(ws + bufsz);
  size_t off = 2u * bufsz;
  unsigned short* wih_h = (unsigned short*)(ws + off);  off += 262144u;
  signed char*    wqb   = (signed char*)(ws + off);     off += 262144u;
  signed char*    hst   = (signed char*)(ws + off);     off += 131072u;
  float*          cst   = (float*)(ws + off);           off += 524288u;
  float*          bcv   = (float*)(ws + off);           off += 4096u;
  float*          scl   = (float*)(ws + off);

  prep1<<<320, 256, 0, stream>>>(whh, h0, wih, bih, bhh, scl, wih_h, bcv);
  prep2<<<256, 256, 0, stream>>>(whh, h0, c0, scl, wqb, hst, cst);

  // prologue: xgemm for chunk 0 (full chip)
  xgemm<<<4 * tc, 256, 0, stream>>>(x, wih_h, bcv, xgb0, 0, tclog);

  int NC = 512 / tc;
  for (int c = 0; c < NC; ++c) {
    unsigned short* cur = (c & 1) ? xgb1 : xgb0;
    unsigned short* nxt = (c & 1) ? xgb0 : xgb1;
    int do_x = (c + 1 < NC) ? 1 : 0;
    fused_chunk<<<256, 1024, 0, stream>>>(
        cur, wqb, scl, hst, cst, out, tc, (c == 0) ? 1 : 0, (c == NC - 1) ? 1 : 0,
        x, wih_h, bcv, nxt, (c + 1) * tc, tclog, do_x);
  }
}

// Round 14
// 498.907 us; speedup vs baseline: 1.0064x; 1.0064x over previous
//
#include <hip/hip_runtime.h>
#include <hip/hip_bf16.h>
#include <hip/hip_fp16.h>

// LSTM: B=512, T=512, I=128, H=256, gates G=4H=1024 (PyTorch i,f,g,o order).
// Round-14: graded wave priority. Step model (closed, matches 2232 cyc):
// [MFMA 1306 lockstep] + [EW ~500 bunched] + [sync ~420] — phases serialize
// because round-robin MFMA arbitration finishes all 4 waves together. Fix:
// wave si runs its MFMA cluster at priority 3-si (s_setprio immediate via
// wave-uniform branch), so clusters drain serially and each wave's EW hides
// under later waves' clusters. No sleeps (R13's skew was re-paid every step
// by the barrier — reverted). Breadth-first MFMA kept. Bit-exact vs R12.

typedef __attribute__((ext_vector_type(4))) float f32x4;
typedef __attribute__((ext_vector_type(8))) _Float16 f16x8;
typedef __attribute__((ext_vector_type(4))) unsigned int u32x4;
typedef __attribute__((ext_vector_type(4))) int i32x4;

static __device__ __forceinline__ float h2f(unsigned short u) {
  return (float)__builtin_bit_cast(_Float16, u);
}
static __device__ __forceinline__ unsigned short f2h(float f) {
  return __builtin_bit_cast(unsigned short, (_Float16)f);
}
static __device__ __forceinline__ float fast_sigmoid(float x) {
  return __builtin_amdgcn_rcpf(1.0f + __builtin_amdgcn_exp2f(-1.44269504f * x));
}
static __device__ __forceinline__ float fast_tanh(float x) {
  return 1.0f - 2.0f * __builtin_amdgcn_rcpf(1.0f + __builtin_amdgcn_exp2f(2.88539008f * x));
}

// ---------------------------------------------------------------- prep kernels
// scl layout (floats): [0]=sw, [1]=sh, [8..135] whh partials, [136..199] h0.
__global__ __launch_bounds__(256) void prep1(
    const float* __restrict__ whh, const float* __restrict__ h0,
    const float* __restrict__ wih, const float* __restrict__ bih,
    const float* __restrict__ bhh,
    float* __restrict__ scl, unsigned short* __restrict__ wih_h,
    float* __restrict__ bcv) {
  const int b = blockIdx.x, tid = threadIdx.x;
  if (b < 192) {
    __shared__ float s[256];
    const float* src = (b < 128) ? whh : h0;
    int base = (b < 128) ? b * 2048 : (b - 128) * 2048;
    float m = 0.f;
#pragma unroll
    for (int i = 0; i < 8; ++i) m = fmaxf(m, fabsf(src[base + i * 256 + tid]));
    s[tid] = m; __syncthreads();
    for (int w = 128; w > 0; w >>= 1) {
      if (tid < w) s[tid] = fmaxf(s[tid], s[tid + w]);
      __syncthreads();
    }
    if (tid == 0) scl[8 + b] = s[0];
  } else {
    // w_ih cast + gate-row interleave: dst row q <- src row (q&3)*256 + (q>>2)
    int i = ((b - 192) * 256 + tid) * 4;  // over 131072
    int q = i >> 7, k = i & 127;
    int p = (q & 3) * 256 + (q >> 2);
    f32x4 v = *(const f32x4*)(wih + p * 128 + k);
    ushort4 pk;
    pk.x = f2h(v[0]); pk.y = f2h(v[1]); pk.z = f2h(v[2]); pk.w = f2h(v[3]);
    *(ushort4*)(wih_h + i) = pk;
    if (b == 192) {
      for (int q2 = tid; q2 < 1024; q2 += 256) {
        int p2 = (q2 & 3) * 256 + (q2 >> 2);
        bcv[q2] = bih[p2] + bhh[p2];
      }
    }
  }
}

__global__ __launch_bounds__(256) void prep2(
    const float* __restrict__ whh, const float* __restrict__ h0,
    const float* __restrict__ c0, float* __restrict__ scl,
    signed char* __restrict__ wq, signed char* __restrict__ hst,
    float* __restrict__ cst) {
  __shared__ float s[256];
  const int b = blockIdx.x, tid = threadIdx.x;
  float v = (tid < 128) ? scl[8 + tid] : 0.f;
  s[tid] = v; __syncthreads();
  for (int w = 128; w > 0; w >>= 1) {
    if (tid < w) s[tid] = fmaxf(s[tid], s[tid + w]);
    __syncthreads();
  }
  float sw = s[0]; __syncthreads();
  v = (tid < 64) ? scl[136 + tid] : 0.f;
  s[tid] = v; __syncthreads();
  for (int w = 128; w > 0; w >>= 1) {
    if (tid < w) s[tid] = fmaxf(s[tid], s[tid + w]);
    __syncthreads();
  }
  float sh = s[0];
  if (b == 0 && tid == 0) { scl[0] = sw; scl[1] = sh; }

  // quantize w_hh (plain layout: row n = gate*256 + col)
  const float invw = 127.0f / sw;
  int base = b * 1024;
#pragma unroll
  for (int i = 0; i < 4; ++i) {
    int idx = base + i * 256 + tid;
    int q = (int)rintf(whh[idx] * invw);
    wq[idx] = (signed char)max(-127, min(127, q));
  }
  // state init
  const float invh = 127.0f / sh;
  int sb = b * 512;
#pragma unroll
  for (int i = 0; i < 2; ++i) {
    int idx = sb + i * 256 + tid;
    int q = (int)rintf(h0[idx] * invh);
    hst[idx] = (signed char)max(-127, min(127, q));
    cst[idx] = c0[idx];
  }
}

// ---------------------------------------------------------------- prologue gemm
__global__ __launch_bounds__(256) void xgemm(
    const float* __restrict__ x, const unsigned short* __restrict__ wih,
    const float* __restrict__ bconv,
    unsigned short* __restrict__ xg, int t0, int tclog) {
  __shared__ unsigned short Ash[128 * 128];
  __shared__ unsigned short Bsh[128 * 128];

  const int tid  = threadIdx.x;
  const int lane = tid & 63;
  const int wv   = tid >> 6;
  const int c16  = lane & 15;
  const int gq   = lane >> 4;
  const long m0  = (long)blockIdx.x * 128;
  const int tcm  = (1 << tclog) - 1;

#pragma unroll
  for (int i = 0; i < 16; ++i) {
    int fidx = (i * 256 + tid) * 4;
    int row = fidx >> 7, k = fidx & 127;
    long cr = m0 + row;
    long b  = cr >> tclog;
    long tl = cr & tcm;
    f32x4 v = *(const f32x4*)(x + ((size_t)b * 512 + t0 + tl) * 128 + k);
    ushort4 pk;
    pk.x = f2h(v[0]); pk.y = f2h(v[1]); pk.z = f2h(v[2]); pk.w = f2h(v[3]);
    int byte = (row * 256 + k * 2) ^ ((row & 7) << 4);
    *(ushort4*)((char*)Ash + byte) = pk;
  }

  const int mh = (wv >> 1) * 64;
  const int nh = (wv & 1) * 64;

  for (int nc = 0; nc < 8; ++nc) {
    __syncthreads();
    {
      const char* wb = (const char*)(wih + nc * 128 * 128);
#pragma unroll
      for (int i = 0; i < 8; ++i) {
        int idx16 = i * 256 + tid;
        int row = idx16 >> 4, ch = idx16 & 15;
        int srcoff = row * 256 + ((ch * 16) ^ ((row & 7) << 4));
        u32x4 v = *(const u32x4*)(wb + srcoff);
        *(u32x4*)((char*)Bsh + idx16 * 16) = v;
      }
    }
    __syncthreads();

    float bias_v[4];
#pragma unroll
    for (int nt = 0; nt < 4; ++nt)
      bias_v[nt] = bconv[nc * 128 + nh + nt * 16 + c16];

    f16x8 af[4][4], bfr[4][4];
#pragma unroll
    for (int sm = 0; sm < 4; ++sm)
#pragma unroll
      for (int kt = 0; kt < 4; ++kt) {
        int m = mh + sm * 16 + c16;
        int byte = (m * 256 + (kt * 32 + gq * 8) * 2) ^ ((m & 7) << 4);
        af[sm][kt] = __builtin_bit_cast(f16x8, *(const u32x4*)((const char*)Ash + byte));
      }
#pragma unroll
    for (int nt = 0; nt < 4; ++nt)
#pragma unroll
      for (int kt = 0; kt < 4; ++kt) {
        int n = nh + nt * 16 + c16;
        int byte = (n * 256 + (kt * 32 + gq * 8) * 2) ^ ((n & 7) << 4);
        bfr[nt][kt] = __builtin_bit_cast(f16x8, *(const u32x4*)((const char*)Bsh + byte));
      }

    f32x4 acc[4][4];
#pragma unroll
    for (int sm = 0; sm < 4; ++sm)
#pragma unroll
      for (int nt = 0; nt < 4; ++nt) { f32x4 z = {0.f, 0.f, 0.f, 0.f}; acc[sm][nt] = z; }
#pragma unroll
    for (int sm = 0; sm < 4; ++sm)
#pragma unroll
      for (int nt = 0; nt < 4; ++nt)
#pragma unroll
        for (int kt = 0; kt < 4; ++kt)
          acc[sm][nt] = __builtin_amdgcn_mfma_f32_16x16x32_f16(af[sm][kt], bfr[nt][kt], acc[sm][nt], 0, 0, 0);

#pragma unroll
    for (int sm = 0; sm < 4; ++sm)
#pragma unroll
      for (int nt = 0; nt < 4; ++nt) {
        long row = m0 + mh + sm * 16 + gq * 4;
        int gcol = nc * 128 + nh + nt * 16 + c16;
#pragma unroll
        for (int r = 0; r < 4; ++r)
          xg[(size_t)(row + r) * 1024 + gcol] = f2h(acc[sm][nt][r] + bias_v[nt]);
      }
  }
}

// ---------------------------------------------------------------- fused kernel
// 1024 threads. blocks 0-127: lstm chunk c (4 rows, 16 waves, 1 output/lane).
// blocks 128-255: xgemm chunk c+1.
__global__ __launch_bounds__(1024)
void fused_chunk(
    const unsigned short* __restrict__ xgc, const signed char* __restrict__ wq,
    const float* __restrict__ scales, signed char* __restrict__ hst,
    float* __restrict__ cst, float* __restrict__ out, int Tc, int first, int last,
    const float* __restrict__ x, const unsigned short* __restrict__ wih,
    const float* __restrict__ bconv, unsigned short* __restrict__ xgn,
    int t0n, int tclog, int do_x) {
  __shared__ char smem[65536];

  const int tid  = threadIdx.x;
  const int lane = tid & 63;
  const int wv   = tid >> 6;      // 0..15
  const int c16  = lane & 15;
  const int gq   = lane >> 4;     // 0..3

  if (blockIdx.x < 128) {
    // ------------------------------ LSTM: rows 0..3 at M-rows {0,4,8,12}
    signed char (*hb)[1152] = (signed char (*)[1152])smem;  // [buf][4 x 288B]
    const int b0 = blockIdx.x * 4;
    const int col = wv * 16 + c16;          // this lane's single output col
    float cv = cst[(b0 + gq) * 256 + col];  // output row = gq

    const float sw   = scales[0] * (1.0f / 127.0f);
    const float facR = sw * (1.0f / 127.0f);
    const float fac0 = first ? sw * (scales[1] * (1.0f / 127.0f)) : facR;

    // weights: gate g, n = g*256 + col, k = kt*64 + gq*16 -> 64 VGPR total
    i32x4 wf[4][4];
#pragma unroll
    for (int g = 0; g < 4; ++g)
#pragma unroll
      for (int kt = 0; kt < 4; ++kt)
        wf[g][kt] = *(const i32x4*)(wq + (g * 256 + col) * 256 + kt * 64 + gq * 16);
#pragma unroll
    for (int g = 0; g < 4; ++g)
#pragma unroll
      for (int kt = 0; kt < 4; ++kt)
        asm volatile("" : "+v"(wf[g][kt]));

    // init hb[0]: rows 0..3 (stride 288B), cols 0..255
    {
      int row = tid >> 8, cc = tid & 255;
      hb[0][row * 288 + cc] = hst[(b0 + row) * 256 + cc];
    }

    // per-lane xg: [row=gq][t][col*4 + gate], 8 B/lane/step
    const char* pxp = (const char*)xgc +
        (((size_t)(b0 + gq) * Tc) * 1024 + (size_t)col * 4) * 2;

    const bool mrow = (c16 & 3) == 0;  // A-lanes: M-rows 0,4,8,12
    const signed char* hpA = &hb[0][(c16 >> 2) * 288 + gq * 16];  // read buf 0
    const signed char* hpB = &hb[1][(c16 >> 2) * 288 + gq * 16];  // read buf 1
    signed char* hwA = &hb[1][gq * 288 + col];  // write buf 1 (even steps)
    signed char* hwB = &hb[0][gq * 288 + col];  // write buf 0 (odd steps)

    // SIMD-local wave index: distinct 0..3 within each SIMD under either
    // round-robin (SIMD=wv&3) or blocked (SIMD=wv>>2) wave->SIMD mapping.
    const int si = (wv >> 2) ^ (wv & 3);

    i32x4 af[4];
#pragma unroll
    for (int kt = 0; kt < 4; ++kt) { i32x4 z = {0, 0, 0, 0}; af[kt] = z; }
    const i32x4 zacc = {0, 0, 0, 0};
    int qlast = 0;

    uint2 pxA = *(const uint2*)pxp; pxp += 2048;   // t=0
    uint2 pxB;

    __syncthreads();

// graded priority: wave si drains its cluster at prio 3-si -> clusters grant
// serially; each wave's EW (at prio 0) hides under later waves' clusters.
#define LSTM_MFMA_CLUSTER(ACC, AF)                                            \
    {                                                                          \
      if (si == 0) __builtin_amdgcn_s_setprio(3);                              \
      else if (si == 1) __builtin_amdgcn_s_setprio(2);                         \
      else if (si == 2) __builtin_amdgcn_s_setprio(1);                         \
      _Pragma("unroll")                                                        \
      for (int g = 0; g < 4; ++g)                                              \
        ACC[g] = __builtin_amdgcn_mfma_i32_16x16x64_i8(AF[0], wf[g][0], zacc, 0, 0, 0); \
      _Pragma("unroll")                                                        \
      for (int kt = 1; kt < 4; ++kt)                                           \
        _Pragma("unroll")                                                      \
        for (int g = 0; g < 4; ++g)                                            \
          ACC[g] = __builtin_amdgcn_mfma_i32_16x16x64_i8(AF[kt], wf[g][kt], ACC[g], 0, 0, 0); \
      __builtin_amdgcn_s_setprio(0);                                           \
    }

#define LSTM_EW(ACC, PX, FAC, HW)                                              \
    {                                                                          \
      float xi  = h2f((unsigned short)(PX.x & 0xffff));                        \
      float xf  = h2f((unsigned short)(PX.x >> 16));                           \
      float xgv = h2f((unsigned short)(PX.y & 0xffff));                        \
      float xo  = h2f((unsigned short)(PX.y >> 16));                           \
      float gi = __builtin_fmaf((float)ACC[0][0], FAC, xi);                    \
      float gf = __builtin_fmaf((float)ACC[1][0], FAC, xf);                    \
      float gg = __builtin_fmaf((float)ACC[2][0], FAC, xgv);                   \
      float go = __builtin_fmaf((float)ACC[3][0], FAC, xo);                    \
      cv = fast_sigmoid(gf) * cv + fast_sigmoid(gi) * fast_tanh(gg);           \
      float hn = fast_sigmoid(go) * fast_tanh(cv);                             \
      qlast = (int)rintf(hn * 127.0f);                                         \
      *HW = (signed char)qlast;                                                \
    }

    for (int tt = 0; tt < Tc; tt += 2) {
      // ---------------- even step (read buf0, write buf1)
      pxB = *(const uint2*)pxp; pxp += 2048;   // xg for odd step (in flight)
      if (mrow) {
        af[0] = *(const i32x4*)(hpA);
        af[1] = *(const i32x4*)(hpA + 64);
        af[2] = *(const i32x4*)(hpA + 128);
        af[3] = *(const i32x4*)(hpA + 192);
      }
      i32x4 accA[4];
      LSTM_MFMA_CLUSTER(accA, af)
      {
        const float facE = (tt == 0) ? fac0 : facR;
        LSTM_EW(accA, pxA, facE, hwA)
      }
      __syncthreads();

      // ---------------- odd step (read buf1, write buf0)
      pxA = *(const uint2*)pxp; pxp += 2048;   // xg for next even step
      if (mrow) {
        af[0] = *(const i32x4*)(hpB);
        af[1] = *(const i32x4*)(hpB + 64);
        af[2] = *(const i32x4*)(hpB + 128);
        af[3] = *(const i32x4*)(hpB + 192);
      }
      i32x4 accB[4];
      LSTM_MFMA_CLUSTER(accB, af)
      LSTM_EW(accB, pxB, facR, hwB)
      __syncthreads();
    }
#undef LSTM_MFMA_CLUSTER
#undef LSTM_EW

    cst[(b0 + gq) * 256 + col] = cv;
    hst[(b0 + gq) * 256 + col] = (signed char)qlast;
    if (last) out[(b0 + gq) * 256 + col] = cv;
  } else if (do_x) {
    // ------------------------------ XGEMM chunk c+1 (1024 thr, 16 waves)
    unsigned short* Ash = (unsigned short*)smem;            // 128x128 f16
    unsigned short* Bsh = (unsigned short*)(smem + 32768);  // 128x128 f16
    const int tcm    = (1 << tclog) - 1;
    const int ntiles = Tc << 2;            // (512*Tc)/128
    const int wm = wv >> 2, wn = wv & 3;   // 4x4 wave grid
    const int mh = wm * 32, nh = wn * 32;

    for (int rt = (int)blockIdx.x - 128; rt < ntiles; rt += 128) {
      const long m0 = (long)rt * 128;
      __syncthreads();  // previous tile's readers done before re-staging

#pragma unroll
      for (int i = 0; i < 4; ++i) {
        int fidx = (i * 1024 + tid) * 4;
        int row = fidx >> 7, k = fidx & 127;
        long cr = m0 + row;
        long b  = cr >> tclog;
        long tl = cr & tcm;
        f32x4 v = *(const f32x4*)(x + ((size_t)b * 512 + t0n + tl) * 128 + k);
        ushort4 pk;
        pk.x = f2h(v[0]); pk.y = f2h(v[1]); pk.z = f2h(v[2]); pk.w = f2h(v[3]);
        int byte = (row * 256 + k * 2) ^ ((row & 7) << 4);
        *(ushort4*)((char*)Ash + byte) = pk;
      }

      for (int nc = 0; nc < 8; ++nc) {
        __syncthreads();
        {
          const char* wb = (const char*)(wih + nc * 128 * 128);
#pragma unroll
          for (int i = 0; i < 2; ++i) {
            int idx16 = i * 1024 + tid;
            int row = idx16 >> 4, ch = idx16 & 15;
            int srcoff = row * 256 + ((ch * 16) ^ ((row & 7) << 4));
            u32x4 v = *(const u32x4*)(wb + srcoff);
            *(u32x4*)((char*)Bsh + idx16 * 16) = v;
          }
        }
        __syncthreads();

        float bias_v[2];
#pragma unroll
        for (int nt = 0; nt < 2; ++nt)
          bias_v[nt] = bconv[nc * 128 + nh + nt * 16 + c16];

        f16x8 af[2][4], bfr[2][4];
#pragma unroll
        for (int sm = 0; sm < 2; ++sm)
#pragma unroll
          for (int kt = 0; kt < 4; ++kt) {
            int m = mh + sm * 16 + c16;
            int byte = (m * 256 + (kt * 32 + gq * 8) * 2) ^ ((m & 7) << 4);
            af[sm][kt] = __builtin_bit_cast(f16x8, *(const u32x4*)((const char*)Ash + byte));
          }
#pragma unroll
        for (int nt = 0; nt < 2; ++nt)
#pragma unroll
          for (int kt = 0; kt < 4; ++kt) {
            int n = nh + nt * 16 + c16;
            int byte = (n * 256 + (kt * 32 + gq * 8) * 2) ^ ((n & 7) << 4);
            bfr[nt][kt] = __builtin_bit_cast(f16x8, *(const u32x4*)((const char*)Bsh + byte));
          }

        f32x4 acc[2][2];
#pragma unroll
        for (int sm = 0; sm < 2; ++sm)
#pragma unroll
          for (int nt = 0; nt < 2; ++nt) { f32x4 z = {0.f, 0.f, 0.f, 0.f}; acc[sm][nt] = z; }
#pragma unroll
        for (int sm = 0; sm < 2; ++sm)
#pragma unroll
          for (int nt = 0; nt < 2; ++nt)
#pragma unroll
            for (int kt = 0; kt < 4; ++kt)
              acc[sm][nt] = __builtin_amdgcn_mfma_f32_16x16x32_f16(af[sm][kt], bfr[nt][kt], acc[sm][nt], 0, 0, 0);

#pragma unroll
        for (int sm = 0; sm < 2; ++sm)
#pragma unroll
          for (int nt = 0; nt < 2; ++nt) {
            long row = m0 + mh + sm * 16 + gq * 4;
            int gcol = nc * 128 + nh + nt * 16 + c16;
#pragma unroll
            for (int r = 0; r < 4; ++r)
              xgn[(size_t)(row + r) * 1024 + gcol] = f2h(acc[sm][nt][r] + bias_v[nt]);
          }
      }
    }
  }
}

// ---------------------------------------------------------------- launch
extern "C" void kernel_launch(void* const* d_in, const int* in_sizes, int n_in,
                              void* d_out, int out_size, void* d_ws, size_t ws_size,
                              hipStream_t stream) {
  const float* x   = (const float*)d_in[0];
  const float* h0  = (const float*)d_in[1];
  const float* c0  = (const float*)d_in[2];
  const float* wih = (const float*)d_in[3];
  const float* whh = (const float*)d_in[4];
  const float* bih = (const float*)d_in[5];
  const float* bhh = (const float*)d_in[6];
  float* out = (float*)d_out;

  const size_t fixed = 262144u /*wih f16*/ + 262144u /*wq*/ + 131072u /*hst*/
                     + 524288u /*cst*/ + 4096u /*bconv*/ + 1024u /*scales*/;
  int tc = 128;  // ws_size caps 2 xg buffers at 2x134MB -> tc=128, NC=4
  while (tc > 4 && 2u * (size_t)512 * tc * 2048 + fixed > ws_size) tc >>= 1;
  int tclog = 31 - __builtin_clz((unsigned)tc);
  size_t bufsz = (size_t)512 * tc * 2048;

  char* ws = (char*)d_ws;
  unsigned short* xgb0  = (unsigned short*)ws;
  unsigned short* xgb1  = (unsigned short*)(ws + bufsz);
  size_t off = 2u * bufsz;
  unsigned short* wih_h = (unsigned short*)(ws + off);  off += 262144u;
  signed char*    wqb   = (signed char*)(ws + off);     off += 262144u;
  signed char*    hst   = (signed char*)(ws + off);     off += 131072u;
  float*          cst   = (float*)(ws + off);           off += 524288u;
  float*          bcv   = (float*)(ws + off);           off += 4096u;
  float*          scl   = (float*)(ws + off);

  prep1<<<320, 256, 0, stream>>>(whh, h0, wih, bih, bhh, scl, wih_h, bcv);
  prep2<<<256, 256, 0, stream>>>(whh, h0, c0, scl, wqb, hst, cst);

  // prologue: xgemm for chunk 0 (full chip)
  xgemm<<<4 * tc, 256, 0, stream>>>(x, wih_h, bcv, xgb0, 0, tclog);

  int NC = 512 / tc;
  for (int c = 0; c < NC; ++c) {
    unsigned short* cur = (c & 1) ? xgb1 : xgb0;
    unsigned short* nxt = (c & 1) ? xgb0 : xgb1;
    int do_x = (c + 1 < NC) ? 1 : 0;
    fused_chunk<<<256, 1024, 0, stream>>>(
        cur, wqb, scl, hst, cst, out, tc, (c == 0) ? 1 : 0, (c == NC - 1) ? 1 : 0,
        x, wih_h, bcv, nxt, (c + 1) * tc, tclog, do_x);
  }
}

// Round 15
// 470.980 us; speedup vs baseline: 1.0661x; 1.0593x over previous
//
#include <hip/hip_runtime.h>
#include <hip/hip_bf16.h>
#include <hip/hip_fp16.h>

// LSTM: B=512, T=512, I=128, H=256, gates G=4H=1024 (PyTorch i,f,g,o order).
// Round-15: R12 cluster reverted (depth-first {g,i,f,o}, uniform setprio(1) —
// R13/R14 scheduler experiments were nulls/regressions). EW algebra trimmed:
// exponent scales folded into xg/fac at GEMM time (xg' = s*(xg+b), s=-log2e
// for i,f,o and +2log2e for g) and paired reciprocals combined:
// sig(i)*tanh(g) = (Eg-1)/[(1+Ei)(1+Eg)], sig(o)*tanh(c) likewise.
// 10 trans -> 8 trans, ~30 fewer VALU cyc/wave/step.

typedef __attribute__((ext_vector_type(4))) float f32x4;
typedef __attribute__((ext_vector_type(8))) _Float16 f16x8;
typedef __attribute__((ext_vector_type(4))) unsigned int u32x4;
typedef __attribute__((ext_vector_type(4))) int i32x4;

static __device__ __forceinline__ float h2f(unsigned short u) {
  return (float)__builtin_bit_cast(_Float16, u);
}
static __device__ __forceinline__ unsigned short f2h(float f) {
  return __builtin_bit_cast(unsigned short, (_Float16)f);
}

// ---------------------------------------------------------------- prep kernels
// scl layout (floats): [0]=sw, [1]=sh, [8..135] whh partials, [136..199] h0.
__global__ __launch_bounds__(256) void prep1(
    const float* __restrict__ whh, const float* __restrict__ h0,
    const float* __restrict__ wih, const float* __restrict__ bih,
    const float* __restrict__ bhh,
    float* __restrict__ scl, unsigned short* __restrict__ wih_h,
    float* __restrict__ bcv) {
  const int b = blockIdx.x, tid = threadIdx.x;
  if (b < 192) {
    __shared__ float s[256];
    const float* src = (b < 128) ? whh : h0;
    int base = (b < 128) ? b * 2048 : (b - 128) * 2048;
    float m = 0.f;
#pragma unroll
    for (int i = 0; i < 8; ++i) m = fmaxf(m, fabsf(src[base + i * 256 + tid]));
    s[tid] = m; __syncthreads();
    for (int w = 128; w > 0; w >>= 1) {
      if (tid < w) s[tid] = fmaxf(s[tid], s[tid + w]);
      __syncthreads();
    }
    if (tid == 0) scl[8 + b] = s[0];
  } else {
    // w_ih cast + gate-row interleave: dst row q <- src row (q&3)*256 + (q>>2)
    int i = ((b - 192) * 256 + tid) * 4;  // over 131072
    int q = i >> 7, k = i & 127;
    int p = (q & 3) * 256 + (q >> 2);
    f32x4 v = *(const f32x4*)(wih + p * 128 + k);
    ushort4 pk;
    pk.x = f2h(v[0]); pk.y = f2h(v[1]); pk.z = f2h(v[2]); pk.w = f2h(v[3]);
    *(ushort4*)(wih_h + i) = pk;
    if (b == 192) {
      for (int q2 = tid; q2 < 1024; q2 += 256) {
        int p2 = (q2 & 3) * 256 + (q2 >> 2);
        bcv[q2] = bih[p2] + bhh[p2];
      }
    }
  }
}

__global__ __launch_bounds__(256) void prep2(
    const float* __restrict__ whh, const float* __restrict__ h0,
    const float* __restrict__ c0, float* __restrict__ scl,
    signed char* __restrict__ wq, signed char* __restrict__ hst,
    float* __restrict__ cst) {
  __shared__ float s[256];
  const int b = blockIdx.x, tid = threadIdx.x;
  float v = (tid < 128) ? scl[8 + tid] : 0.f;
  s[tid] = v; __syncthreads();
  for (int w = 128; w > 0; w >>= 1) {
    if (tid < w) s[tid] = fmaxf(s[tid], s[tid + w]);
    __syncthreads();
  }
  float sw = s[0]; __syncthreads();
  v = (tid < 64) ? scl[136 + tid] : 0.f;
  s[tid] = v; __syncthreads();
  for (int w = 128; w > 0; w >>= 1) {
    if (tid < w) s[tid] = fmaxf(s[tid], s[tid + w]);
    __syncthreads();
  }
  float sh = s[0];
  if (b == 0 && tid == 0) { scl[0] = sw; scl[1] = sh; }

  // quantize w_hh (plain layout: row n = gate*256 + col)
  const float invw = 127.0f / sw;
  int base = b * 1024;
#pragma unroll
  for (int i = 0; i < 4; ++i) {
    int idx = base + i * 256 + tid;
    int q = (int)rintf(whh[idx] * invw);
    wq[idx] = (signed char)max(-127, min(127, q));
  }
  // state init
  const float invh = 127.0f / sh;
  int sb = b * 512;
#pragma unroll
  for (int i = 0; i < 2; ++i) {
    int idx = sb + i * 256 + tid;
    int q = (int)rintf(h0[idx] * invh);
    hst[idx] = (signed char)max(-127, min(127, q));
    cst[idx] = c0[idx];
  }
}

// ---------------------------------------------------------------- prologue gemm
// writes PRE-SCALED xg': col q (gate = q&3 = c16&3) scaled by s_gate.
__global__ __launch_bounds__(256) void xgemm(
    const float* __restrict__ x, const unsigned short* __restrict__ wih,
    const float* __restrict__ bconv,
    unsigned short* __restrict__ xg, int t0, int tclog) {
  __shared__ unsigned short Ash[128 * 128];
  __shared__ unsigned short Bsh[128 * 128];

  const int tid  = threadIdx.x;
  const int lane = tid & 63;
  const int wv   = tid >> 6;
  const int c16  = lane & 15;
  const int gq   = lane >> 4;
  const long m0  = (long)blockIdx.x * 128;
  const int tcm  = (1 << tclog) - 1;
  const float sc = ((c16 & 3) == 2) ? 2.88539008f : -1.44269504f;

#pragma unroll
  for (int i = 0; i < 16; ++i) {
    int fidx = (i * 256 + tid) * 4;
    int row = fidx >> 7, k = fidx & 127;
    long cr = m0 + row;
    long b  = cr >> tclog;
    long tl = cr & tcm;
    f32x4 v = *(const f32x4*)(x + ((size_t)b * 512 + t0 + tl) * 128 + k);
    ushort4 pk;
    pk.x = f2h(v[0]); pk.y = f2h(v[1]); pk.z = f2h(v[2]); pk.w = f2h(v[3]);
    int byte = (row * 256 + k * 2) ^ ((row & 7) << 4);
    *(ushort4*)((char*)Ash + byte) = pk;
  }

  const int mh = (wv >> 1) * 64;
  const int nh = (wv & 1) * 64;

  for (int nc = 0; nc < 8; ++nc) {
    __syncthreads();
    {
      const char* wb = (const char*)(wih + nc * 128 * 128);
#pragma unroll
      for (int i = 0; i < 8; ++i) {
        int idx16 = i * 256 + tid;
        int row = idx16 >> 4, ch = idx16 & 15;
        int srcoff = row * 256 + ((ch * 16) ^ ((row & 7) << 4));
        u32x4 v = *(const u32x4*)(wb + srcoff);
        *(u32x4*)((char*)Bsh + idx16 * 16) = v;
      }
    }
    __syncthreads();

    float bias_v[4];
#pragma unroll
    for (int nt = 0; nt < 4; ++nt)
      bias_v[nt] = bconv[nc * 128 + nh + nt * 16 + c16];

    f16x8 af[4][4], bfr[4][4];
#pragma unroll
    for (int sm = 0; sm < 4; ++sm)
#pragma unroll
      for (int kt = 0; kt < 4; ++kt) {
        int m = mh + sm * 16 + c16;
        int byte = (m * 256 + (kt * 32 + gq * 8) * 2) ^ ((m & 7) << 4);
        af[sm][kt] = __builtin_bit_cast(f16x8, *(const u32x4*)((const char*)Ash + byte));
      }
#pragma unroll
    for (int nt = 0; nt < 4; ++nt)
#pragma unroll
      for (int kt = 0; kt < 4; ++kt) {
        int n = nh + nt * 16 + c16;
        int byte = (n * 256 + (kt * 32 + gq * 8) * 2) ^ ((n & 7) << 4);
        bfr[nt][kt] = __builtin_bit_cast(f16x8, *(const u32x4*)((const char*)Bsh + byte));
      }

    f32x4 acc[4][4];
#pragma unroll
    for (int sm = 0; sm < 4; ++sm)
#pragma unroll
      for (int nt = 0; nt < 4; ++nt) { f32x4 z = {0.f, 0.f, 0.f, 0.f}; acc[sm][nt] = z; }
#pragma unroll
    for (int sm = 0; sm < 4; ++sm)
#pragma unroll
      for (int nt = 0; nt < 4; ++nt)
#pragma unroll
        for (int kt = 0; kt < 4; ++kt)
          acc[sm][nt] = __builtin_amdgcn_mfma_f32_16x16x32_f16(af[sm][kt], bfr[nt][kt], acc[sm][nt], 0, 0, 0);

#pragma unroll
    for (int sm = 0; sm < 4; ++sm)
#pragma unroll
      for (int nt = 0; nt < 4; ++nt) {
        long row = m0 + mh + sm * 16 + gq * 4;
        int gcol = nc * 128 + nh + nt * 16 + c16;
#pragma unroll
        for (int r = 0; r < 4; ++r)
          xg[(size_t)(row + r) * 1024 + gcol] = f2h(sc * (acc[sm][nt][r] + bias_v[nt]));
      }
  }
}

// ---------------------------------------------------------------- fused kernel
// 1024 threads. blocks 0-127: lstm chunk c (4 rows, 16 waves, 1 output/lane).
// blocks 128-255: xgemm chunk c+1.
__global__ __launch_bounds__(1024)
void fused_chunk(
    const unsigned short* __restrict__ xgc, const signed char* __restrict__ wq,
    const float* __restrict__ scales, signed char* __restrict__ hst,
    float* __restrict__ cst, float* __restrict__ out, int Tc, int first, int last,
    const float* __restrict__ x, const unsigned short* __restrict__ wih,
    const float* __restrict__ bconv, unsigned short* __restrict__ xgn,
    int t0n, int tclog, int do_x) {
  __shared__ char smem[65536];

  const int tid  = threadIdx.x;
  const int lane = tid & 63;
  const int wv   = tid >> 6;      // 0..15
  const int c16  = lane & 15;
  const int gq   = lane >> 4;     // 0..3

  if (blockIdx.x < 128) {
    // ------------------------------ LSTM: rows 0..3 at M-rows {0,4,8,12}
    signed char (*hb)[1152] = (signed char (*)[1152])smem;  // [buf][4 x 288B]
    const int b0 = blockIdx.x * 4;
    const int col = wv * 16 + c16;          // this lane's single output col
    float cv = cst[(b0 + gq) * 256 + col];  // output row = gq

    const float sw   = scales[0] * (1.0f / 127.0f);
    const float facR = sw * (1.0f / 127.0f);
    const float fac0 = first ? sw * (scales[1] * (1.0f / 127.0f)) : facR;
    const float facIR = -1.44269504f * facR, facGR = 2.88539008f * facR;
    const float facI0 = -1.44269504f * fac0, facG0 = 2.88539008f * fac0;

    // weights: gate g, n = g*256 + col, k = kt*64 + gq*16 -> 64 VGPR total
    i32x4 wf[4][4];
#pragma unroll
    for (int g = 0; g < 4; ++g)
#pragma unroll
      for (int kt = 0; kt < 4; ++kt)
        wf[g][kt] = *(const i32x4*)(wq + (g * 256 + col) * 256 + kt * 64 + gq * 16);
#pragma unroll
    for (int g = 0; g < 4; ++g)
#pragma unroll
      for (int kt = 0; kt < 4; ++kt)
        asm volatile("" : "+v"(wf[g][kt]));

    // init hb[0]: rows 0..3 (stride 288B), cols 0..255
    {
      int row = tid >> 8, cc = tid & 255;
      hb[0][row * 288 + cc] = hst[(b0 + row) * 256 + cc];
    }

    // per-lane xg: [row=gq][t][col*4 + gate], 8 B/lane/step (pre-scaled)
    const char* pxp = (const char*)xgc +
        (((size_t)(b0 + gq) * Tc) * 1024 + (size_t)col * 4) * 2;

    const bool mrow = (c16 & 3) == 0;  // A-lanes: M-rows 0,4,8,12
    const signed char* hpA = &hb[0][(c16 >> 2) * 288 + gq * 16];  // read buf 0
    const signed char* hpB = &hb[1][(c16 >> 2) * 288 + gq * 16];  // read buf 1
    signed char* hwA = &hb[1][gq * 288 + col];  // write buf 1 (even steps)
    signed char* hwB = &hb[0][gq * 288 + col];  // write buf 0 (odd steps)

    i32x4 af[4];
#pragma unroll
    for (int kt = 0; kt < 4; ++kt) { i32x4 z = {0, 0, 0, 0}; af[kt] = z; }
    const i32x4 zacc = {0, 0, 0, 0};
    int qlast = 0;

    uint2 pxA = *(const uint2*)pxp; pxp += 2048;   // t=0
    uint2 pxB;

    __syncthreads();

// R12-proven cluster: depth-first per gate, order g(2), i(0), f(1), o(3);
// uniform setprio(1) around the cluster.
#define LSTM_MFMA_CLUSTER(ACC, AF)                                            \
    {                                                                          \
      __builtin_amdgcn_s_setprio(1);                                           \
      const int go_[4] = {2, 0, 1, 3};                                         \
      _Pragma("unroll")                                                        \
      for (int gi_ = 0; gi_ < 4; ++gi_) {                                      \
        const int g = go_[gi_];                                                \
        ACC[g] = __builtin_amdgcn_mfma_i32_16x16x64_i8(AF[0], wf[g][0], zacc, 0, 0, 0); \
        _Pragma("unroll")                                                      \
        for (int kt = 1; kt < 4; ++kt)                                         \
          ACC[g] = __builtin_amdgcn_mfma_i32_16x16x64_i8(AF[kt], wf[g][kt], ACC[g], 0, 0, 0); \
      }                                                                        \
      __builtin_amdgcn_s_setprio(0);                                           \
    }

// xg is pre-scaled: arg_i = facI*acc + xi' gives -log2e*gate directly, etc.
// sig(i)*tanh(g) = (Eg-1)/[(1+Ei)(1+Eg)]; sig(o)*tanh(c) likewise (1 rcp each).
// fmin clamps keep den finite -> no inf*0 NaN; saturation matches old form.
#define LSTM_EW(ACC, PX, FI, FG, HW)                                           \
    {                                                                          \
      float xi  = h2f((unsigned short)(PX.x & 0xffff));                        \
      float xf  = h2f((unsigned short)(PX.x >> 16));                           \
      float xgv = h2f((unsigned short)(PX.y & 0xffff));                        \
      float xo  = h2f((unsigned short)(PX.y >> 16));                           \
      float Ei = __builtin_amdgcn_exp2f(__builtin_fmaf((float)ACC[0][0], FI, xi)); \
      float Ef = __builtin_amdgcn_exp2f(__builtin_fmaf((float)ACC[1][0], FI, xf)); \
      float Eg = __builtin_amdgcn_exp2f(fminf(__builtin_fmaf((float)ACC[2][0], FG, xgv), 126.f)); \
      float Eo = __builtin_amdgcn_exp2f(__builtin_fmaf((float)ACC[3][0], FI, xo)); \
      float t1 = (Eg - 1.f) * __builtin_amdgcn_rcpf((1.f + Ei) * (1.f + Eg));  \
      cv = __builtin_fmaf(__builtin_amdgcn_rcpf(1.f + Ef), cv, t1);            \
      float Ec = __builtin_amdgcn_exp2f(fminf(2.88539008f * cv, 126.f));       \
      float hn = (Ec - 1.f) * __builtin_amdgcn_rcpf((1.f + Eo) * (1.f + Ec));  \
      qlast = (int)rintf(hn * 127.0f);                                         \
      *HW = (signed char)qlast;                                                \
    }

    for (int tt = 0; tt < Tc; tt += 2) {
      // ---------------- even step (read buf0, write buf1)
      pxB = *(const uint2*)pxp; pxp += 2048;   // xg for odd step (in flight)
      if (mrow) {
        af[0] = *(const i32x4*)(hpA);
        af[1] = *(const i32x4*)(hpA + 64);
        af[2] = *(const i32x4*)(hpA + 128);
        af[3] = *(const i32x4*)(hpA + 192);
      }
      i32x4 accA[4];
      LSTM_MFMA_CLUSTER(accA, af)
      {
        const float fI = (tt == 0) ? facI0 : facIR;
        const float fG = (tt == 0) ? facG0 : facGR;
        LSTM_EW(accA, pxA, fI, fG, hwA)
      }
      __syncthreads();

      // ---------------- odd step (read buf1, write buf0)
      pxA = *(const uint2*)pxp; pxp += 2048;   // xg for next even step
      if (mrow) {
        af[0] = *(const i32x4*)(hpB);
        af[1] = *(const i32x4*)(hpB + 64);
        af[2] = *(const i32x4*)(hpB + 128);
        af[3] = *(const i32x4*)(hpB + 192);
      }
      i32x4 accB[4];
      LSTM_MFMA_CLUSTER(accB, af)
      LSTM_EW(accB, pxB, facIR, facGR, hwB)
      __syncthreads();
    }
#undef LSTM_MFMA_CLUSTER
#undef LSTM_EW

    cst[(b0 + gq) * 256 + col] = cv;
    hst[(b0 + gq) * 256 + col] = (signed char)qlast;
    if (last) out[(b0 + gq) * 256 + col] = cv;
  } else if (do_x) {
    // ------------------------------ XGEMM chunk c+1 (1024 thr, 16 waves)
    unsigned short* Ash = (unsigned short*)smem;            // 128x128 f16
    unsigned short* Bsh = (unsigned short*)(smem + 32768);  // 128x128 f16
    const int tcm    = (1 << tclog) - 1;
    const int ntiles = Tc << 2;            // (512*Tc)/128
    const int wm = wv >> 2, wn = wv & 3;   // 4x4 wave grid
    const int mh = wm * 32, nh = wn * 32;
    const float sc = ((c16 & 3) == 2) ? 2.88539008f : -1.44269504f;

    for (int rt = (int)blockIdx.x - 128; rt < ntiles; rt += 128) {
      const long m0 = (long)rt * 128;
      __syncthreads();  // previous tile's readers done before re-staging

#pragma unroll
      for (int i = 0; i < 4; ++i) {
        int fidx = (i * 1024 + tid) * 4;
        int row = fidx >> 7, k = fidx & 127;
        long cr = m0 + row;
        long b  = cr >> tclog;
        long tl = cr & tcm;
        f32x4 v = *(const f32x4*)(x + ((size_t)b * 512 + t0n + tl) * 128 + k);
        ushort4 pk;
        pk.x = f2h(v[0]); pk.y = f2h(v[1]); pk.z = f2h(v[2]); pk.w = f2h(v[3]);
        int byte = (row * 256 + k * 2) ^ ((row & 7) << 4);
        *(ushort4*)((char*)Ash + byte) = pk;
      }

      for (int nc = 0; nc < 8; ++nc) {
        __syncthreads();
        {
          const char* wb = (const char*)(wih + nc * 128 * 128);
#pragma unroll
          for (int i = 0; i < 2; ++i) {
            int idx16 = i * 1024 + tid;
            int row = idx16 >> 4, ch = idx16 & 15;
            int srcoff = row * 256 + ((ch * 16) ^ ((row & 7) << 4));
            u32x4 v = *(const u32x4*)(wb + srcoff);
            *(u32x4*)((char*)Bsh + idx16 * 16) = v;
          }
        }
        __syncthreads();

        float bias_v[2];
#pragma unroll
        for (int nt = 0; nt < 2; ++nt)
          bias_v[nt] = bconv[nc * 128 + nh + nt * 16 + c16];

        f16x8 af[2][4], bfr[2][4];
#pragma unroll
        for (int sm = 0; sm < 2; ++sm)
#pragma unroll
          for (int kt = 0; kt < 4; ++kt) {
            int m = mh + sm * 16 + c16;
            int byte = (m * 256 + (kt * 32 + gq * 8) * 2) ^ ((m & 7) << 4);
            af[sm][kt] = __builtin_bit_cast(f16x8, *(const u32x4*)((const char*)Ash + byte));
          }
#pragma unroll
        for (int nt = 0; nt < 2; ++nt)
#pragma unroll
          for (int kt = 0; kt < 4; ++kt) {
            int n = nh + nt * 16 + c16;
            int byte = (n * 256 + (kt * 32 + gq * 8) * 2) ^ ((n & 7) << 4);
            bfr[nt][kt] = __builtin_bit_cast(f16x8, *(const u32x4*)((const char*)Bsh + byte));
          }

        f32x4 acc[2][2];
#pragma unroll
        for (int sm = 0; sm < 2; ++sm)
#pragma unroll
          for (int nt = 0; nt < 2; ++nt) { f32x4 z = {0.f, 0.f, 0.f, 0.f}; acc[sm][nt] = z; }
#pragma unroll
        for (int sm = 0; sm < 2; ++sm)
#pragma unroll
          for (int nt = 0; nt < 2; ++nt)
#pragma unroll
            for (int kt = 0; kt < 4; ++kt)
              acc[sm][nt] = __builtin_amdgcn_mfma_f32_16x16x32_f16(af[sm][kt], bfr[nt][kt], acc[sm][nt], 0, 0, 0);

#pragma unroll
        for (int sm = 0; sm < 2; ++sm)
#pragma unroll
          for (int nt = 0; nt < 2; ++nt) {
            long row = m0 + mh + sm * 16 + gq * 4;
            int gcol = nc * 128 + nh + nt * 16 + c16;
#pragma unroll
            for (int r = 0; r < 4; ++r)
              xgn[(size_t)(row + r) * 1024 + gcol] = f2h(sc * (acc[sm][nt][r] + bias_v[nt]));
          }
      }
    }
  }
}

// ---------------------------------------------------------------- launch
extern "C" void kernel_launch(void* const* d_in, const int* in_sizes, int n_in,
                              void* d_out, int out_size, void* d_ws, size_t ws_size,
                              hipStream_t stream) {
  const float* x   = (const float*)d_in[0];
  const float* h0  = (const float*)d_in[1];
  const float* c0  = (const float*)d_in[2];
  const float* wih = (const float*)d_in[3];
  const float* whh = (const float*)d_in[4];
  const float* bih = (const float*)d_in[5];
  const float* bhh = (const float*)d_in[6];
  float* out = (float*)d_out;

  const size_t fixed = 262144u /*wih f16*/ + 262144u /*wq*/ + 131072u /*hst*/
                     + 524288u /*cst*/ + 4096u /*bconv*/ + 1024u /*scales*/;
  int tc = 128;  // ws_size caps 2 xg buffers at 2x134MB -> tc=128, NC=4
  while (tc > 4 && 2u * (size_t)512 * tc * 2048 + fixed > ws_size) tc >>= 1;
  int tclog = 31 - __builtin_clz((unsigned)tc);
  size_t bufsz = (size_t)512 * tc * 2048;

  char* ws = (char*)d_ws;
  unsigned short* xgb0  = (unsigned short*)ws;
  unsigned short* xgb1  = (unsigned short*)(ws + bufsz);
  size_t off = 2u * bufsz;
  unsigned short* wih_h = (unsigned short*)(ws + off);  off += 262144u;
  signed char*    wqb   = (signed char*)(ws + off);     off += 262144u;
  signed char*    hst   = (signed char*)(ws + off);     off += 131072u;
  float*          cst   = (float*)(ws + off);           off += 524288u;
  float*          bcv   = (float*)(ws + off);           off += 4096u;
  float*          scl   = (float*)(ws + off);

  prep1<<<320, 256, 0, stream>>>(whh, h0, wih, bih, bhh, scl, wih_h, bcv);
  prep2<<<256, 256, 0, stream>>>(whh, h0, c0, scl, wqb, hst, cst);

  // prologue: xgemm for chunk 0 (full chip)
  xgemm<<<4 * tc, 256, 0, stream>>>(x, wih_h, bcv, xgb0, 0, tclog);

  int NC = 512 / tc;
  for (int c = 0; c < NC; ++c) {
    unsigned short* cur = (c & 1) ? xgb1 : xgb0;
    unsigned short* nxt = (c & 1) ? xgb0 : xgb1;
    int do_x = (c + 1 < NC) ? 1 : 0;
    fused_chunk<<<256, 1024, 0, stream>>>(
        cur, wqb, scl, hst, cst, out, tc, (c == 0) ? 1 : 0, (c == NC - 1) ? 1 : 0,
        x, wih_h, bcv, nxt, (c + 1) * tc, tclog, do_x);
  }
}